// Round 10
// baseline (282.728 us; speedup 1.0000x reference)
//
#include <hip/hip_runtime.h>
#include <hip/hip_bf16.h>
#include <hip/hip_fp16.h>

// Problem dims (fixed by setup_inputs)
#define BB 8
#define SS 2048
#define DD 1024
#define DKK 128
#define N_ITEMS 2560   // 8 batches x sum_t ceil((16t+16)/512): 32x1+32x2+32x3+32x4

using bf16x8  = __attribute__((ext_vector_type(8))) __bf16;
using floatx4 = __attribute__((ext_vector_type(4))) float;
using intx4   = __attribute__((ext_vector_type(4))) int;
using halfx8  = __attribute__((ext_vector_type(8))) _Float16;

// async global->LDS, 16B/lane. LDS dest = wave-uniform base + lane*16 (HW rule).
__device__ __forceinline__ void lds16(const void* g, void* l) {
    __builtin_amdgcn_global_load_lds((const __attribute__((address_space(1))) void*)g,
                                     (__attribute__((address_space(3))) void*)l, 16, 0, 0);
}

__device__ __forceinline__ int pack2(float a, float b) {
    union { __bf16 h; unsigned short u; } ua, ub;
    ua.h = (__bf16)a; ub.h = (__bf16)b;
    return (int)(ua.u | ((unsigned)ub.u << 16));
}

// ---------------------------------------------------------------------------
// Kernel 0: W (fp32 [128][1024]) -> bf16, k-tile-major + 16B-block XOR swizzle
// ---------------------------------------------------------------------------
__global__ __launch_bounds__(256) void convw_kernel(
    const float* __restrict__ Wq, const float* __restrict__ Wk,
    const float* __restrict__ Wv, __bf16* __restrict__ Wt)
{
    const int z = blockIdx.y;
    const float* W = (z == 0) ? Wq : (z == 1) ? Wk : Wv;
    const int t  = blockIdx.x * 256 + threadIdx.x;   // 0..16383
    const int n  = t >> 7;
    const int k0 = (t & 127) * 8;
    float4 f0 = *(const float4*)(W + n * DD + k0);
    float4 f1 = *(const float4*)(W + n * DD + k0 + 4);
    bf16x8 v;
    v[0]=(__bf16)f0.x; v[1]=(__bf16)f0.y; v[2]=(__bf16)f0.z; v[3]=(__bf16)f0.w;
    v[4]=(__bf16)f1.x; v[5]=(__bf16)f1.y; v[6]=(__bf16)f1.z; v[7]=(__bf16)f1.w;
    const int kb  = (k0 >> 3) & 7;
    const int kbs = kb ^ (n & 7);
    *(bf16x8*)(Wt + (size_t)z * 131072 + ((k0 >> 6) * 128 + n) * 64 + kbs * 8) = v;
}

// ---------------------------------------------------------------------------
// Kernel 1: projections. 1024 blocks x 256 thr: bx<512 = fused Q&K (ctx read
// ONCE, both W tiles in LDS, 16 MFMA/step/wave); bx>=512 = V. BM=32, BK=64.
// LDS 37.4 KB -> 4 blocks/CU.
// ---------------------------------------------------------------------------
__global__ __launch_bounds__(256, 4) void proj_kernel(
    const float* __restrict__ x, const float* __restrict__ ctx,
    const __bf16* __restrict__ Wt, const int* __restrict__ lengths,
    __bf16* __restrict__ Qb, __bf16* __restrict__ Kb, __bf16* __restrict__ Vt)
{
    __shared__ __align__(16) __bf16 SH[18688];      // 37376 B
    __bf16* Abuf = SH;                              // 32x72 = 2304
    __bf16* Wl0  = SH + 2304;                       // 128x64 swizzled image
    __bf16* Wl1  = SH + 10496;                      // (QK blocks only)
    __bf16* T    = SH;                              // V epilogue overlay 128x40

    const int isV = blockIdx.x >= 512;
    const int m0  = (isV ? blockIdx.x - 512 : blockIdx.x) * 32;
    const int b   = m0 >> 11;
    const int s0  = m0 & (SS - 1);
    const int len = lengths[b];
    if (s0 >= len) return;                          // outputs never read / p=0

    const int tid  = threadIdx.x;
    const int wave = tid >> 6;
    const int lane = tid & 63;
    const int quad = lane >> 4;
    const int l16  = lane & 15;
    const int wm   = wave >> 1;                     // 16-row half
    const int wn   = wave & 1;                      // 64-col half

    const float*  A  = isV ? x : ctx;
    const __bf16* W0 = isV ? (Wt + 262144) : Wt;    // V : Q
    const __bf16* W1 = Wt + 131072;                 // K

    const int r    = tid >> 3;                      // 0..31
    const int kseg = (tid & 7) * 8;
    const float* Ab = A + (size_t)(m0 + r) * DD + kseg;

    floatx4 acc0[4], acc1[4];
#pragma unroll
    for (int nt = 0; nt < 4; ++nt) {
        acc0[nt] = (floatx4){0.f,0.f,0.f,0.f};
        acc1[nt] = (floatx4){0.f,0.f,0.f,0.f};
    }

    float4 pf0 = *(const float4*)Ab;
    float4 pf1 = *(const float4*)(Ab + 4);

    for (int t = 0; t < 16; ++t) {
        __syncthreads();                            // done reading SH (step t-1)
        {
            bf16x8 cv;
            cv[0]=(__bf16)pf0.x; cv[1]=(__bf16)pf0.y; cv[2]=(__bf16)pf0.z; cv[3]=(__bf16)pf0.w;
            cv[4]=(__bf16)pf1.x; cv[5]=(__bf16)pf1.y; cv[6]=(__bf16)pf1.z; cv[7]=(__bf16)pf1.w;
            *(bf16x8*)&Abuf[r * 72 + kseg] = cv;
        }
#pragma unroll
        for (int i = 0; i < 4; ++i) {               // 16 chunks of 1 KB each mat
            const int c = wave * 4 + i;
            lds16(W0 + (size_t)t * 8192 + c * 512 + lane * 8, Wl0 + c * 512);
            if (!isV)
                lds16(W1 + (size_t)t * 8192 + c * 512 + lane * 8, Wl1 + c * 512);
        }
        if (t < 15) {
            const float* ap = Ab + (t + 1) * 64;
            pf0 = *(const float4*)ap;
            pf1 = *(const float4*)(ap + 4);
        }
        __syncthreads();                            // staging visible

#pragma unroll
        for (int kh = 0; kh < 2; ++kh) {
            bf16x8 af = *(const bf16x8*)&Abuf[(wm*16 + l16) * 72 + kh*32 + quad*8];
            const int kb = kh * 4 + quad;
#pragma unroll
            for (int nt = 0; nt < 4; ++nt) {
                const int n = wn * 64 + nt * 16 + l16;
                const int off = n * 64 + ((kb ^ (n & 7)) << 3);
                bf16x8 w0 = *(const bf16x8*)&Wl0[off];
                acc0[nt] = __builtin_amdgcn_mfma_f32_16x16x32_bf16(af, w0, acc0[nt], 0, 0, 0);
                if (!isV) {
                    bf16x8 w1 = *(const bf16x8*)&Wl1[off];
                    acc1[nt] = __builtin_amdgcn_mfma_f32_16x16x32_bf16(af, w1, acc1[nt], 0, 0, 0);
                }
            }
        }
    }

    if (!isV) {
#pragma unroll
        for (int rr = 0; rr < 4; ++rr) {
            const int row = m0 + wm*16 + quad*4 + rr;
            const float mk = ((row & (SS - 1)) < len) ? 1.f : 0.f;
#pragma unroll
            for (int nt = 0; nt < 4; ++nt) {
                const int col = wn*64 + nt*16 + l16;
                Qb[(size_t)row * DKK + col] = (__bf16)(acc0[nt][rr] * mk);
                Kb[(size_t)row * DKK + col] = (__bf16)(acc1[nt][rr] * mk);
            }
        }
    } else {
        __syncthreads();                            // done reading Wl/Abuf
#pragma unroll
        for (int nt = 0; nt < 4; ++nt)
#pragma unroll
            for (int rr = 0; rr < 4; ++rr) {
                const int s = wm*16 + quad*4 + rr;
                const int n = wn*64 + nt*16 + l16;
                const float mk = (s0 + s < len) ? 1.f : 0.f;
                T[n * 40 + s] = (__bf16)(acc0[nt][rr] * mk);
            }
        __syncthreads();
        const int n = tid >> 1, h = tid & 1;
        __bf16* dst = Vt + (size_t)b * DKK * SS + (size_t)n * SS + s0 + h * 16;
        *(bf16x8*)dst       = *(const bf16x8*)&T[n * 40 + h * 16];
        *(bf16x8*)(dst + 8) = *(const bf16x8*)&T[n * 40 + h * 16 + 8];
    }
}

// ---------------------------------------------------------------------------
// Kernel 2: attention partials. 2560 single-wave blocks, longest-first.
// Pad q-tiles are NOT skipped: Q rows there are 0 -> p = exp(-8) uniform ->
// O/l = column mean of valid V exactly (constant p cancels) — replaces the
// vmean kernel and fin's branch at ~zero extra cost (short items).
// K register dbuf + hoisted V loads; bpermute C->A transform (fence-free).
// ---------------------------------------------------------------------------
__global__ __launch_bounds__(64) void attn_part_kernel(
    const __bf16* __restrict__ Qb, const __bf16* __restrict__ Kb,
    const __bf16* __restrict__ Vt, const int* __restrict__ lengths,
    _Float16* __restrict__ Opart, float* __restrict__ Lpart)
{
    const int f  = N_ITEMS - 1 - blockIdx.x;   // longest items dispatch first
    const int b  = f / 320;
    const int r0 = f - b * 320;
    const int g  = (r0 < 32) ? 0 : (r0 < 96) ? 1 : (r0 < 192) ? 2 : 3;
    const int r_ = r0 - 16 * g * (g + 1);
    const int t0 = 32 * g + r_ / (g + 1);
    const int kc = r_ - (t0 - 32 * g) * (g + 1);

    const int qw  = t0 * 16;
    const int len = lengths[b];
    const int jmax = min(qw + 16, len);        // pad tiles: jmax = len (run them)
    const int jlo  = kc * 512;
    if (jlo >= jmax) return;                   // fin's nv excludes this
    const int jhi = min(jlo + 512, jmax);

    const int lane = threadIdx.x;
    const int quad = lane >> 4;
    const int l16  = lane & 15;

    const __bf16* Qbase = Qb + (size_t)(b * SS + qw) * DKK;
    const __bf16* Kbase = Kb + (size_t)b * SS * DKK;
    const __bf16* Vbase = Vt + (size_t)b * DKK * SS;

    bf16x8 qfrag[4];
#pragma unroll
    for (int cc = 0; cc < 4; ++cc)
        qfrag[cc] = *(const bf16x8*)(Qbase + (size_t)l16 * DKK + cc * 32 + quad * 8);

    floatx4 oacc[8];
#pragma unroll
    for (int nt = 0; nt < 8; ++nt) oacc[nt] = (floatx4){0.f,0.f,0.f,0.f};
    float lsum = 0.f;                          // per-lane, q = l16
    const float scale = 0.08838834764831845f;  // 1/sqrt(128)
    const int   iq    = qw + l16;

    auto loadK = [&](int j0, bf16x8* kf) {
#pragma unroll
        for (int jt = 0; jt < 2; ++jt)
#pragma unroll
            for (int cc = 0; cc < 4; ++cc)
                kf[jt * 4 + cc] = *(const bf16x8*)(
                    Kbase + (size_t)(j0 + jt*16 + l16) * DKK + cc*32 + quad*8);
    };
    auto body = [&](int j0, const bf16x8* kf) {
        bf16x8 vf[8];                          // issues early, used at the end
#pragma unroll
        for (int nt = 0; nt < 8; ++nt)
            vf[nt] = *(const bf16x8*)(Vbase + (size_t)(nt*16 + l16) * SS + j0 + quad*8);

        // S^T[key][q]: A = K-frag (m=key), B = Q-frag (n=q)
        floatx4 st[2];
#pragma unroll
        for (int jt = 0; jt < 2; ++jt) {
            st[jt] = (floatx4){0.f,0.f,0.f,0.f};
#pragma unroll
            for (int cc = 0; cc < 4; ++cc)
                st[jt] = __builtin_amdgcn_mfma_f32_16x16x32_bf16(
                    kf[jt*4 + cc], qfrag[cc], st[jt], 0, 0, 0);
        }
        int pk[2][2];
#pragma unroll
        for (int jt = 0; jt < 2; ++jt) {
            float p[4];
#pragma unroll
            for (int rr = 0; rr < 4; ++rr) {
                const int j = j0 + jt*16 + quad*4 + rr;
                p[rr] = (j > iq || j >= len) ? 0.f : __expf(st[jt][rr] * scale - 8.f);
                lsum += p[rr];
            }
            pk[jt][0] = pack2(p[0], p[1]);
            pk[jt][1] = pack2(p[2], p[3]);
        }
        // C->A layout via cross-lane pull (verified R5/R6)
        const int a0 = (((quad & 1) << 5) + l16) << 2;
        const int a1 = a0 + 64;
        const int r00 = __builtin_amdgcn_ds_bpermute(a0, pk[0][0]);
        const int r01 = __builtin_amdgcn_ds_bpermute(a0, pk[0][1]);
        const int r02 = __builtin_amdgcn_ds_bpermute(a0, pk[1][0]);
        const int r03 = __builtin_amdgcn_ds_bpermute(a0, pk[1][1]);
        const int r10 = __builtin_amdgcn_ds_bpermute(a1, pk[0][0]);
        const int r11 = __builtin_amdgcn_ds_bpermute(a1, pk[0][1]);
        const int r12 = __builtin_amdgcn_ds_bpermute(a1, pk[1][0]);
        const int r13 = __builtin_amdgcn_ds_bpermute(a1, pk[1][1]);
        const bool hi = quad >= 2;
        union { intx4 i; bf16x8 h; } u;
        u.i = (intx4){ hi ? r02 : r00, hi ? r03 : r01,
                       hi ? r12 : r10, hi ? r13 : r11 };
#pragma unroll
        for (int nt = 0; nt < 8; ++nt)
            oacc[nt] = __builtin_amdgcn_mfma_f32_16x16x32_bf16(u.h, vf[nt], oacc[nt], 0, 0, 0);
    };

    bf16x8 kf0[8], kf1[8];
    int j0 = jlo;
    loadK(j0, kf0);
    while (true) {
        if (j0 + 32 < jhi) loadK(j0 + 32, kf1);
        body(j0, kf0);
        j0 += 32; if (j0 >= jhi) break;
        if (j0 + 32 < jhi) loadK(j0 + 32, kf0);
        body(j0, kf1);
        j0 += 32; if (j0 >= jhi) break;
    }

    lsum += __shfl_xor(lsum, 16, 64);
    lsum += __shfl_xor(lsum, 32, 64);
    if (lane < 16) Lpart[f * 16 + l16] = lsum;
#pragma unroll
    for (int nt = 0; nt < 8; ++nt)
#pragma unroll
        for (int rr = 0; rr < 4; ++rr)
            Opart[(size_t)f * 2048 + (quad*4 + rr) * 128 + nt*16 + l16] =
                (_Float16)oacc[nt][rr];
}

// ---------------------------------------------------------------------------
// Kernel 3: finalize — merge <=4 partials per tile, divide by l. No branches:
// pad tiles flow through the same path (their partials hold the uniform sums).
// ---------------------------------------------------------------------------
__global__ __launch_bounds__(256) void attn_fin_kernel(
    const _Float16* __restrict__ Opart, const float* __restrict__ Lpart,
    const int* __restrict__ lengths, float* __restrict__ out)
{
    const int tile = blockIdx.x;               // 0..1023
    const int b    = tile >> 7;
    const int t0   = tile & 127;
    const int qw   = t0 * 16;
    const int len  = lengths[b];
    const int row  = threadIdx.x >> 4;
    const int c8   = (threadIdx.x & 15) * 8;
    float* op = out + (size_t)(b * SS + qw + row) * DKK + c8;

    const int g     = t0 >> 5;
    const int jmax  = min(qw + 16, len);
    const int nv    = min(g + 1, (jmax + 511) >> 9);
    const int fbase = b * 320 + 16 * g * (g + 1) + (t0 - 32 * g) * (g + 1);

    float l = 0.f;
    float o[8] = {0.f,0.f,0.f,0.f,0.f,0.f,0.f,0.f};
    for (int i = 0; i < nv; ++i) {
        l += Lpart[(fbase + i) * 16 + row];
        halfx8 h8 = *(const halfx8*)(Opart + (size_t)(fbase + i) * 2048 + row * 128 + c8);
#pragma unroll
        for (int k = 0; k < 8; ++k) o[k] += (float)h8[k];
    }
    const float inv = 1.f / l;
#pragma unroll
    for (int k = 0; k < 8; ++k) op[k] = o[k] * inv;
}

extern "C" void kernel_launch(void* const* d_in, const int* in_sizes, int n_in,
                              void* d_out, int out_size, void* d_ws, size_t ws_size,
                              hipStream_t stream) {
    const float* x   = (const float*)d_in[0];
    const float* ctx = (const float*)d_in[1];
    const float* Wq  = (const float*)d_in[2];
    const float* Wk  = (const float*)d_in[3];
    const float* Wv  = (const float*)d_in[4];
    const int* lengths = (const int*)d_in[5];
    float* out = (float*)d_out;

    char* ws = (char*)d_ws;
    __bf16*   Wt = (__bf16*)ws;                        // 768 KB (tiled+swizzled)
    __bf16*   Qb = (__bf16*)(ws + 786432);             // 4 MB
    __bf16*   Kb = (__bf16*)(ws + 4980736);            // 4 MB
    __bf16*   Vt = (__bf16*)(ws + 9175040);            // 4 MB (V^T)
    float*    Lp = (float*)  (ws + 13369344);          // 160 KB
    _Float16* Op = (_Float16*)(ws + 13533184);         // 10 MB (total ~22.9 MB)

    convw_kernel<<<dim3(64, 3), 256, 0, stream>>>(Wq, Wk, Wv, Wt);
    proj_kernel<<<1024, 256, 0, stream>>>(x, ctx, Wt, lengths, Qb, Kb, Vt);
    attn_part_kernel<<<N_ITEMS, 64, 0, stream>>>(Qb, Kb, Vt, lengths, Op, Lp);
    attn_fin_kernel<<<1024, 256, 0, stream>>>(Op, Lp, lengths, out);
}